// Round 2
// baseline (512.882 us; speedup 1.0000x reference)
//
#include <hip/hip_runtime.h>

typedef short v8s __attribute__((ext_vector_type(8)));
typedef float v4f __attribute__((ext_vector_type(4)));

#define BH 16384             // B*H
#define TBH 33554432         // T*B*H
#define TSEG 256             // timesteps per scan segment
#define NSEG 8               // 2048 / TSEG

__device__ __forceinline__ ushort f2bf(float f) {
  // round-to-nearest-even fp32 -> bf16 (inputs finite)
  uint u = __float_as_uint(f);
  u += 0x7FFF + ((u >> 16) & 1);
  return (ushort)(u >> 16);
}

// ---------------- Phase 1: xW[m,h] = sum_i x[m,i] * W[h,i], bf16 MFMA ----------------
// BM=128, BN=128, BK=64. blockIdx = mb*2 + nb (n fastest -> adjacent blocks share A tile).
// LDS 36 KB -> 3-4 blocks/CU so barrier stalls overlap across blocks.
__global__ __launch_bounds__(256, 3) void indrnn_gemm(
    const float* __restrict__ A,
    const float* __restrict__ W,
    ushort* __restrict__ C)
{
  __shared__ ushort As[128 * 72];
  __shared__ ushort Bs[128 * 72];

  const int tid  = threadIdx.x;
  const int lane = tid & 63;
  const int wid  = tid >> 6;    // 0..3
  const int wm   = wid >> 1;    // 0..1
  const int wn   = wid & 1;     // 0..1
  const int mb   = blockIdx.x >> 1;
  const int nb   = blockIdx.x & 1;
  const int m0   = mb * 128;
  const int n0   = nb * 128;

  const int l15 = lane & 15;
  const int lhi = lane >> 4;    // 0..3

  v4f acc[4][4] = {};

  for (int kc = 0; kc < 4; ++kc) {
    // stage A tile: 128 rows x 64 k (fp32 -> bf16): 2048 float4 over 256 threads
    #pragma unroll
    for (int j = 0; j < 8; ++j) {
      int f    = j * 256 + tid;
      int row  = f >> 4;
      int colf = f & 15;
      const float4 a4 = *(const float4*)(A + ((size_t)(m0 + row) << 8) + kc * 64 + colf * 4);
      *(ushort4*)(As + row * 72 + colf * 4) =
          make_ushort4(f2bf(a4.x), f2bf(a4.y), f2bf(a4.z), f2bf(a4.w));
    }
    // stage B tile (W half): 128 rows x 64 k
    #pragma unroll
    for (int j = 0; j < 8; ++j) {
      int f    = j * 256 + tid;
      int row  = f >> 4;
      int colf = f & 15;
      const float4 a4 = *(const float4*)(W + ((size_t)(n0 + row) << 8) + kc * 64 + colf * 4);
      *(ushort4*)(Bs + row * 72 + colf * 4) =
          make_ushort4(f2bf(a4.x), f2bf(a4.y), f2bf(a4.z), f2bf(a4.w));
    }
    __syncthreads();

    #pragma unroll
    for (int kk = 0; kk < 2; ++kk) {
      const int koff = kk * 32 + lhi * 8;
      v8s af[4], bf[4];
      #pragma unroll
      for (int mt = 0; mt < 4; ++mt)
        af[mt] = *(const v8s*)(As + (wm * 64 + mt * 16 + l15) * 72 + koff);
      #pragma unroll
      for (int nt = 0; nt < 4; ++nt)
        bf[nt] = *(const v8s*)(Bs + (wn * 64 + nt * 16 + l15) * 72 + koff);
      #pragma unroll
      for (int mt = 0; mt < 4; ++mt)
        #pragma unroll
        for (int nt = 0; nt < 4; ++nt)
          acc[mt][nt] = __builtin_amdgcn_mfma_f32_16x16x32_bf16(af[mt], bf[nt], acc[mt][nt], 0, 0, 0);
    }
    __syncthreads();
  }

  // epilogue: C/D layout col=lane&15, row=(lane>>4)*4+reg
  #pragma unroll
  for (int mt = 0; mt < 4; ++mt) {
    #pragma unroll
    for (int nt = 0; nt < 4; ++nt) {
      #pragma unroll
      for (int r = 0; r < 4; ++r) {
        int row = m0 + wm * 64 + mt * 16 + lhi * 4 + r;
        int col = n0 + wn * 64 + nt * 16 + l15;
        C[((size_t)row << 8) + col] = f2bf(acc[mt][nt][r]);
      }
    }
  }
}

// ---------------- Phase 2: chained-segment scan ----------------
// 2048 blocks (8 segs x 256 channel-groups), 64 threads; all co-resident (8 waves/CU).
// Segment s waits for segment s-1's last h via the output value itself:
// producer atomically stores h+1.0 (h >= 0 from relu; poison 0xAA < 0, memset 0 < 1
// both keep the consumer spinning), consumer reads it, fixes the value up.
__global__ __launch_bounds__(64, 2) void indrnn_scan(
    const ushort* __restrict__ xw,
    const float* __restrict__ h0,
    const float* __restrict__ w_hh,
    float* __restrict__ out)
{
  const int s  = blockIdx.x >> 8;    // segment 0..7 (slow-varying: deps point backward)
  const int g  = blockIdx.x & 255;   // channel group
  const int ch = g * 64 + threadIdx.x;
  const float w = w_hh[ch & 255];
  const int t0 = s * TSEG;
  const ushort* px = xw + (size_t)t0 * BH + ch;
  float* po = out + (size_t)t0 * BH + ch;

  // Prefetch + pack the whole segment (256 t) into 128 VGPRs BEFORE the handoff spin,
  // so the serial chain runs entirely out of registers.
  uint pk[TSEG / 2];
  #pragma unroll
  for (int j = 0; j < TSEG / 2; ++j) {
    uint lo = px[(size_t)(2 * j) * BH];
    uint hi = px[(size_t)(2 * j + 1) * BH];
    pk[j] = lo | (hi << 16);
  }

  float h;
  if (s == 0) {
    h = h0[ch];
  } else {
    float* sig = out + ((size_t)t0 - 1) * (size_t)BH + ch;
    float v;
    do {
      v = __hip_atomic_load(sig, __ATOMIC_RELAXED, __HIP_MEMORY_SCOPE_AGENT);
    } while (!(v >= 1.0f));
    h = v - 1.0f;
    __hip_atomic_store(sig, h, __ATOMIC_RELAXED, __HIP_MEMORY_SCOPE_AGENT);  // fix up signal slot
  }

  #pragma unroll
  for (int j = 0; j < TSEG / 2; ++j) {
    float x0 = __uint_as_float(pk[j] << 16);
    h = fmaxf(fmaf(h, w, x0), 0.0f);
    po[(size_t)(2 * j) * BH] = h;

    float x1 = __uint_as_float(pk[j] & 0xFFFF0000u);
    h = fmaxf(fmaf(h, w, x1), 0.0f);
    if (j == TSEG / 2 - 1) {
      if (s == NSEG - 1) {
        po[(size_t)(2 * j + 1) * BH] = h;
        out[(size_t)TBH + ch] = h;            // h_last output
      } else {
        __hip_atomic_store(&po[(size_t)(2 * j + 1) * BH], h + 1.0f,
                           __ATOMIC_RELAXED, __HIP_MEMORY_SCOPE_AGENT);  // signal next segment
      }
    } else {
      po[(size_t)(2 * j + 1) * BH] = h;
    }
  }
}

extern "C" void kernel_launch(void* const* d_in, const int* in_sizes, int n_in,
                              void* d_out, int out_size, void* d_ws, size_t ws_size,
                              hipStream_t stream) {
  const float* x    = (const float*)d_in[0];   // [2048, 64, 256]
  const float* h0   = (const float*)d_in[1];   // [1, 64, 256]
  const float* W_ih = (const float*)d_in[2];   // [256, 256]
  const float* w_hh = (const float*)d_in[3];   // [256]
  float* out = (float*)d_out;                  // [T,B,H] ++ [1,B,H]
  ushort* xw = (ushort*)d_ws;                  // bf16 intermediate, 64 MB

  indrnn_gemm<<<dim3(2048), dim3(256), 0, stream>>>(x, W_ih, xw);
  indrnn_scan<<<dim3(2048), dim3(64), 0, stream>>>(xw, h0, w_hh, out);
}

// Round 3
// 301.725 us; speedup vs baseline: 1.6998x; 1.6998x over previous
//
#include <hip/hip_runtime.h>

typedef short v8s __attribute__((ext_vector_type(8)));
typedef float v4f __attribute__((ext_vector_type(4)));

#define BH 16384             // B*H
#define TBH 33554432         // T*B*H
#define CT 128               // scan chunk timesteps
#define NC 16                // 2048 / CT

__device__ __forceinline__ ushort f2bf(float f) {
  // round-to-nearest-even fp32 -> bf16 (inputs finite)
  uint u = __float_as_uint(f);
  u += 0x7FFF + ((u >> 16) & 1);
  return (ushort)(u >> 16);
}

// ---------------- Phase 1: xW[m,h] = sum_i x[m,i] * W[h,i], bf16 MFMA ----------------
// Round-1 proven structure (BM=128, BN=256, BK=64, 512 thr) + register prefetch of the
// next A k-chunk so the HBM latency overlaps the MFMA phase instead of the barrier.
__global__ __launch_bounds__(512) void indrnn_gemm(
    const float* __restrict__ A,
    const float* __restrict__ W,
    ushort* __restrict__ C)
{
  __shared__ ushort As[128 * 72];
  __shared__ ushort Bs[256 * 72];

  const int tid  = threadIdx.x;
  const int lane = tid & 63;
  const int wid  = tid >> 6;    // 0..7
  const int wm   = wid >> 2;    // 0..1  (M dim, 64 rows each)
  const int wn   = wid & 3;     // 0..3  (N dim, 64 cols each)
  const int m0   = blockIdx.x * 128;

  const int l15 = lane & 15;
  const int lhi = lane >> 4;    // 0..3

  // per-thread A staging coords (4 float4s per chunk)
  int arow[4], acolf[4];
  #pragma unroll
  for (int j = 0; j < 4; ++j) {
    int f = j * 512 + tid;
    arow[j]  = f >> 4;
    acolf[j] = f & 15;
  }

  float4 pa[4];
  #pragma unroll
  for (int j = 0; j < 4; ++j)   // prefetch chunk 0 of A
    pa[j] = *(const float4*)(A + ((size_t)(m0 + arow[j]) << 8) + acolf[j] * 4);

  v4f acc[4][4] = {};

  for (int kc = 0; kc < 4; ++kc) {
    // A tile from prefetch regs -> bf16 -> LDS
    #pragma unroll
    for (int j = 0; j < 4; ++j)
      *(ushort4*)(As + arow[j] * 72 + acolf[j] * 4) =
          make_ushort4(f2bf(pa[j].x), f2bf(pa[j].y), f2bf(pa[j].z), f2bf(pa[j].w));
    // B tile (W, L2-resident after first block) direct
    #pragma unroll
    for (int j = 0; j < 8; ++j) {
      int f    = j * 512 + tid;
      int row  = f >> 4;
      int colf = f & 15;
      const float4 a4 = *(const float4*)(W + ((size_t)row << 8) + kc * 64 + colf * 4);
      *(ushort4*)(Bs + row * 72 + colf * 4) =
          make_ushort4(f2bf(a4.x), f2bf(a4.y), f2bf(a4.z), f2bf(a4.w));
    }
    __syncthreads();

    if (kc < 3) {  // issue next A chunk now; latency overlaps MFMA below
      #pragma unroll
      for (int j = 0; j < 4; ++j)
        pa[j] = *(const float4*)(A + ((size_t)(m0 + arow[j]) << 8) + (kc + 1) * 64 + acolf[j] * 4);
    }

    #pragma unroll
    for (int kk = 0; kk < 2; ++kk) {
      const int koff = kk * 32 + lhi * 8;
      v8s af[4], bf[4];
      #pragma unroll
      for (int mt = 0; mt < 4; ++mt)
        af[mt] = *(const v8s*)(As + (wm * 64 + mt * 16 + l15) * 72 + koff);
      #pragma unroll
      for (int nt = 0; nt < 4; ++nt)
        bf[nt] = *(const v8s*)(Bs + (wn * 64 + nt * 16 + l15) * 72 + koff);
      #pragma unroll
      for (int mt = 0; mt < 4; ++mt)
        #pragma unroll
        for (int nt = 0; nt < 4; ++nt)
          acc[mt][nt] = __builtin_amdgcn_mfma_f32_16x16x32_bf16(af[mt], bf[nt], acc[mt][nt], 0, 0, 0);
    }
    __syncthreads();
  }

  // epilogue: C/D layout col=lane&15, row=(lane>>4)*4+reg  (verified in round 1)
  #pragma unroll
  for (int mt = 0; mt < 4; ++mt) {
    #pragma unroll
    for (int nt = 0; nt < 4; ++nt) {
      #pragma unroll
      for (int r = 0; r < 4; ++r) {
        int row = m0 + wm * 64 + mt * 16 + lhi * 4 + r;
        int col = wn * 64 + nt * 16 + l15;
        C[((size_t)row << 8) + col] = f2bf(acc[mt][nt][r]);
      }
    }
  }
}

// ---------------- Phase 2: producer-consumer scan ----------------
// 256 blocks x 256 threads; block owns 64 channels. Wave 0 runs the serial recurrence
// out of LDS; waves 1-3 stream xw->LDS (in) and h->global (out), double-buffered in
// 128-step chunks. No cross-block communication. LDS 96 KB -> 1 block/CU.
__global__ __launch_bounds__(256) void indrnn_scan(
    const ushort* __restrict__ xw,
    const float* __restrict__ h0,
    const float* __restrict__ w_hh,
    float* __restrict__ out)
{
  __shared__ alignas(16) ushort xin[2][CT * 64];   // 32 KB
  __shared__ alignas(16) float  xout[2][CT * 64];  // 64 KB

  const int tid  = threadIdx.x;
  const int wave = tid >> 6;
  const int lane = tid & 63;
  const int ch0  = blockIdx.x * 64;

  if (wave == 0) {
    // ---- serial compute wave ----
    const int ch = ch0 + lane;
    const float w = w_hh[ch & 255];
    float h = h0[ch];
    __syncthreads();                    // B0: xin[0] filled
    for (int c = 0; c < NC; ++c) {
      const ushort* xi = xin[c & 1];
      float*        xo = xout[c & 1];
      #pragma unroll
      for (int t = 0; t < CT; ++t) {
        float xv = __uint_as_float(((uint)xi[t * 64 + lane]) << 16);
        h = fmaxf(fmaf(h, w, xv), 0.0f);
        xo[t * 64 + lane] = h;
      }
      __syncthreads();                  // B(c+1)
    }
    out[(size_t)TBH + ch] = h;          // h_last
  } else {
    // ---- copy waves (192 lanes) ----
    const int cl = tid - 64;

    // prefill chunk 0
    for (int i = cl; i < CT * 16; i += 192) {
      int t  = i >> 4;
      int c4 = (i & 15) * 4;
      *(ushort4*)(&xin[0][t * 64 + c4]) =
          *(const ushort4*)(xw + (size_t)t * BH + ch0 + c4);
    }
    __syncthreads();                    // B0

    for (int c = 0; c < NC; ++c) {
      if (c + 1 < NC) {                 // load chunk c+1 into the other buffer
        const ushort* src = xw + (size_t)(c + 1) * CT * BH + ch0;
        ushort* dst = xin[(c + 1) & 1];
        for (int i = cl; i < CT * 16; i += 192) {
          int t  = i >> 4;
          int c4 = (i & 15) * 4;
          *(ushort4*)(dst + t * 64 + c4) = *(const ushort4*)(src + (size_t)t * BH + c4);
        }
      }
      if (c > 0) {                      // drain chunk c-1 results to global
        const float* src = xout[(c - 1) & 1];
        float* dst = out + (size_t)(c - 1) * CT * BH + ch0;
        for (int i = cl; i < CT * 16; i += 192) {
          int t  = i >> 4;
          int c4 = (i & 15) * 4;
          *(float4*)(dst + (size_t)t * BH + c4) = *(const float4*)(src + t * 64 + c4);
        }
      }
      __syncthreads();                  // B(c+1)
    }
    // final drain (compute wave is done; buffers no longer contended)
    {
      const float* src = xout[(NC - 1) & 1];
      float* dst = out + (size_t)(NC - 1) * CT * BH + ch0;
      for (int i = cl; i < CT * 16; i += 192) {
        int t  = i >> 4;
        int c4 = (i & 15) * 4;
        *(float4*)(dst + (size_t)t * BH + c4) = *(const float4*)(src + t * 64 + c4);
      }
    }
  }
}

extern "C" void kernel_launch(void* const* d_in, const int* in_sizes, int n_in,
                              void* d_out, int out_size, void* d_ws, size_t ws_size,
                              hipStream_t stream) {
  const float* x    = (const float*)d_in[0];   // [2048, 64, 256]
  const float* h0   = (const float*)d_in[1];   // [1, 64, 256]
  const float* W_ih = (const float*)d_in[2];   // [256, 256]
  const float* w_hh = (const float*)d_in[3];   // [256]
  float* out = (float*)d_out;                  // [T,B,H] ++ [1,B,H]
  ushort* xw = (ushort*)d_ws;                  // bf16 intermediate, 64 MB

  indrnn_gemm<<<dim3(1024), dim3(512), 0, stream>>>(x, W_ih, xw);
  indrnn_scan<<<dim3(256), dim3(256), 0, stream>>>(xw, h0, w_hh, out);
}